// Round 1
// 2566.298 us; speedup vs baseline: 1.1819x; 1.1819x over previous
//
#include <hip/hip_runtime.h>
#include <hip/hip_bf16.h>
#include <math.h>

typedef __hip_bfloat16 bf16;
typedef __bf16 bf16x8 __attribute__((ext_vector_type(8)));
typedef __bf16 bf16x4 __attribute__((ext_vector_type(4)));
typedef float floatx4 __attribute__((ext_vector_type(4)));

#define BB 512
#define TT 80
#define DD 540
#define HH 6
#define KK 90
#define LL 6
#define HK 540      // H*K
#define N3 1620     // 3*H*K
#define BT 40960    // B*T
#define TD 43200    // T*D
#define KP 544      // GEMM K padded (17 * 32)
#define NQ 1664     // qkv N padded (13 * 128)
#define NF 640      // ff N padded (5 * 128)
#define TP 104      // attn LDS row stride (96 + 8 pad)

__device__ inline float toF(bf16 x) { return __bfloat162float(x); }

// ---------------- weight prep (runs every launch; graph-safe) ----------------

__global__ void prep_wqkv(const float* __restrict__ Wq,
                          const float* __restrict__ Wk,
                          const float* __restrict__ Wv,
                          bf16* __restrict__ wTt) {
    int idx = blockIdx.x * blockDim.x + threadIdx.x;
    const int total = LL * NQ * KP;
    if (idx >= total) return;
    int k = idx % KP;
    int n = (idx / KP) % NQ;
    int l = idx / (KP * NQ);
    float v = 0.f;
    if (k < DD && n < N3) {
        int sel = n / HK;
        int nn = n - sel * HK;
        int h = nn / KK, kk = nn - h * KK;
        const float* W = (sel == 0) ? Wq : ((sel == 1) ? Wk : Wv);
        v = W[(((size_t)l * HH + h) * DD + k) * KK + kk];
    }
    wTt[idx] = __float2bfloat16(v);
}

__global__ void prep_wt(const float* __restrict__ W, bf16* __restrict__ Wt) {
    int idx = blockIdx.x * blockDim.x + threadIdx.x;
    const int total = LL * NF * KP;
    if (idx >= total) return;
    int k = idx % KP;
    int n = (idx / KP) % NF;
    int l = idx / (KP * NF);
    float v = 0.f;
    if (k < DD && n < DD)
        v = W[((size_t)l * DD + k) * DD + n];
    Wt[idx] = __float2bfloat16(v);
}

__global__ void embed_kernel(const int* __restrict__ ids,
                             const float* __restrict__ embed,
                             const float* __restrict__ pos,
                             bf16* __restrict__ xc, int rows) {
    int idx = blockIdx.x * blockDim.x + threadIdx.x;
    int total = rows * KP;
    if (idx >= total) return;
    int d = idx % KP;
    int bt = idx / KP;
    float v = 0.f;
    if (d < DD) {
        int t = bt % TT;
        v = embed[(size_t)ids[bt] * DD + d] + pos[t * DD + d];
    }
    xc[idx] = __float2bfloat16(v);
}

// ---------------- MFMA GEMM (R9 structure + bijective XCD swizzle) ----------------
__global__ __launch_bounds__(256) void mfma_gemm(
    const bf16* __restrict__ A, int lda,
    const bf16* __restrict__ Bt,
    bf16* __restrict__ C, int ldc, int Nreal,
    const float* __restrict__ bias, int relu)
{
    __shared__ bf16 As[128 * 32];
    __shared__ bf16 Bs[128 * 32];
    const int t = threadIdx.x;
    const int lane = t & 63;
    const int wave = t >> 6;
    const int wm = (wave & 1) * 64;
    const int wn = (wave >> 1) * 64;

    // XCD-aware bijective swizzle: HW assigns block `orig` to XCD orig%8.
    // Remap so each XCD owns a contiguous chunk of work-ids; consecutive
    // work-ids share the same A row-panel (x = N dim is fastest) -> A is
    // fetched once per XCD-chunk instead of once per XCD per panel.
    int bx = blockIdx.x, by = blockIdx.y;
    {
        int nwg = gridDim.x * gridDim.y;
        if ((nwg & 7) == 0) {
            int orig = by * gridDim.x + bx;
            int per = nwg >> 3;
            int swz = (orig & 7) * per + (orig >> 3);
            bx = swz % gridDim.x;
            by = swz / gridDim.x;
        }
    }
    const int row0 = by * 128;
    const int col0 = bx * 128;
    const int q = lane >> 4, r = lane & 15;

    floatx4 acc[4][4];
#pragma unroll
    for (int i = 0; i < 4; ++i)
#pragma unroll
        for (int j = 0; j < 4; ++j) acc[i][j] = (floatx4){0.f, 0.f, 0.f, 0.f};

    const int sm = t >> 2;
    const int sgo = ((t & 3) ^ ((t >> 3) & 3)) * 8;
    const int slo = (t & 3) * 8;
    const bf16* Ab = A + (size_t)row0 * lda;
    const bf16* Bb = Bt + (size_t)col0 * KP;
    const int ksw = (q ^ ((r >> 1) & 3)) * 8;

    for (int k0 = 0; k0 < KP; k0 += 32) {
        __builtin_amdgcn_global_load_lds(
            (const __attribute__((address_space(1))) void*)(Ab + (size_t)sm * lda + k0 + sgo),
            (__attribute__((address_space(3))) void*)(As + sm * 32 + slo), 16, 0, 0);
        __builtin_amdgcn_global_load_lds(
            (const __attribute__((address_space(1))) void*)(Ab + (size_t)(64 + sm) * lda + k0 + sgo),
            (__attribute__((address_space(3))) void*)(As + (64 + sm) * 32 + slo), 16, 0, 0);
        __builtin_amdgcn_global_load_lds(
            (const __attribute__((address_space(1))) void*)(Bb + (size_t)sm * KP + k0 + sgo),
            (__attribute__((address_space(3))) void*)(Bs + sm * 32 + slo), 16, 0, 0);
        __builtin_amdgcn_global_load_lds(
            (const __attribute__((address_space(1))) void*)(Bb + (size_t)(64 + sm) * KP + k0 + sgo),
            (__attribute__((address_space(3))) void*)(Bs + (64 + sm) * 32 + slo), 16, 0, 0);
        __syncthreads();

        bf16x8 af[4], bfr[4];
#pragma unroll
        for (int i = 0; i < 4; ++i)
            af[i] = *(const bf16x8*)(As + (wm + i * 16 + r) * 32 + ksw);
#pragma unroll
        for (int j = 0; j < 4; ++j)
            bfr[j] = *(const bf16x8*)(Bs + (wn + j * 16 + r) * 32 + ksw);
#pragma unroll
        for (int i = 0; i < 4; ++i)
#pragma unroll
            for (int j = 0; j < 4; ++j)
                acc[i][j] = __builtin_amdgcn_mfma_f32_16x16x32_bf16(
                    af[i], bfr[j], acc[i][j], 0, 0, 0);
        __syncthreads();
    }

#pragma unroll
    for (int i = 0; i < 4; ++i) {
        int m0 = row0 + wm + i * 16 + q * 4;
#pragma unroll
        for (int j = 0; j < 4; ++j) {
            int n = col0 + wn + j * 16 + r;
            bool valid = (n < Nreal);
            float bv = (valid && bias) ? bias[n] : 0.f;
#pragma unroll
            for (int reg = 0; reg < 4; ++reg) {
                float v = acc[i][j][reg] + bv;
                if (relu) v = fmaxf(v, 0.f);
                if (!valid) v = 0.f;
                C[(size_t)(m0 + reg) * ldc + n] = __float2bfloat16(v);
            }
        }
    }
}

// ---------------- MFMA attention (unchanged) ----------------
__global__ __launch_bounds__(320) void attn_mfma(const bf16* __restrict__ qkv,
                                                 bf16* __restrict__ obuf) {
    extern __shared__ bf16 lds[];
    bf16* Qs = lds;                    // 80*TP
    bf16* Ks = lds + 80 * TP;          // 80*TP (becomes P)
    bf16* Vt = lds + 160 * TP;         // 96*TP
    const int b = blockIdx.x / HH, h = blockIdx.x % HH;
    const int tid = threadIdx.x;
    const int lane = tid & 63;
    const int w = tid >> 6;            // wave 0..4
    const int q = lane >> 4, r = lane & 15;
    const bf16* base = qkv + (size_t)b * TT * NQ + h * KK;

    for (int i = tid; i < TT * 12; i += 320) {
        int t = i / 12, kg = i % 12;
        const bf16* qr2 = base + (size_t)t * NQ + kg * 8;
        const bf16* kr2 = qr2 + HK;
        const bf16* vr2 = qr2 + 2 * HK;
        bf16* qd = Qs + t * TP + kg * 8;
        bf16* kd = Ks + t * TP + kg * 8;
#pragma unroll
        for (int j = 0; j < 8; ++j) {
            int k = kg * 8 + j;
            bool ok = (k < KK);
            qd[j] = ok ? qr2[j] : __float2bfloat16(0.f);
            kd[j] = ok ? kr2[j] : __float2bfloat16(0.f);
            Vt[(kg * 8 + j) * TP + t] = ok ? vr2[j] : __float2bfloat16(0.f);
        }
    }
    for (int i = tid; i < 96 * 2; i += 320) {
        int kv = i >> 1, sg = i & 1;
        *(bf16x8*)(Vt + kv * TP + 80 + sg * 8) = (bf16x8)(__bf16)0.0f;
    }
    __syncthreads();

    floatx4 acc[5];
#pragma unroll
    for (int i = 0; i < 5; ++i) acc[i] = (floatx4){0.f, 0.f, 0.f, 0.f};
    bf16x8 bf[3];
#pragma unroll
    for (int ks = 0; ks < 3; ++ks)
        bf[ks] = *(const bf16x8*)(Ks + (16 * w + r) * TP + ks * 32 + q * 8);
#pragma unroll
    for (int ti = 0; ti < 5; ++ti) {
#pragma unroll
        for (int ks = 0; ks < 3; ++ks) {
            bf16x8 af = *(const bf16x8*)(Qs + (16 * ti + r) * TP + ks * 32 + q * 8);
            acc[ti] = __builtin_amdgcn_mfma_f32_16x16x32_bf16(af, bf[ks], acc[ti], 0, 0, 0);
        }
    }

    const float scale = 0.105409255338946f;  // 90^-0.5
    float m = -1e30f;
#pragma unroll
    for (int ti = 0; ti < 5; ++ti)
#pragma unroll
        for (int reg = 0; reg < 4; ++reg) {
            acc[ti][reg] *= scale;
            m = fmaxf(m, acc[ti][reg]);
        }
    m = fmaxf(m, __shfl_xor(m, 16));
    m = fmaxf(m, __shfl_xor(m, 32));
    float sum = 0.f;
    float e[5][4];
#pragma unroll
    for (int ti = 0; ti < 5; ++ti)
#pragma unroll
        for (int reg = 0; reg < 4; ++reg) {
            e[ti][reg] = __expf(acc[ti][reg] - m);
            sum += e[ti][reg];
        }
    sum += __shfl_xor(sum, 16);
    sum += __shfl_xor(sum, 32);
    float inv = 1.f / sum;

    __syncthreads();

    bf16* P = Ks;
#pragma unroll
    for (int ti = 0; ti < 5; ++ti)
#pragma unroll
        for (int reg = 0; reg < 4; ++reg)
            P[(16 * ti + q * 4 + reg) * TP + 16 * w + r] =
                __float2bfloat16(e[ti][reg] * inv);
    for (int i = tid; i < TT * 2; i += 320) {
        int t2 = i >> 1, sg = i & 1;
        *(bf16x8*)(P + t2 * TP + 80 + sg * 8) = (bf16x8)(__bf16)0.0f;
    }
    __syncthreads();

    bf16x8 af2[3];
#pragma unroll
    for (int ks = 0; ks < 3; ++ks)
        af2[ks] = *(const bf16x8*)(P + (16 * w + r) * TP + ks * 32 + q * 8);
    bf16* ob = obuf + ((size_t)b * TT) * NF + h * KK;
#pragma unroll
    for (int nt = 0; nt < 6; ++nt) {
        floatx4 o = (floatx4){0.f, 0.f, 0.f, 0.f};
#pragma unroll
        for (int ks = 0; ks < 3; ++ks) {
            bf16x8 bv = *(const bf16x8*)(Vt + (16 * nt + r) * TP + ks * 32 + q * 8);
            o = __builtin_amdgcn_mfma_f32_16x16x32_bf16(af2[ks], bv, o, 0, 0, 0);
        }
        int kv = 16 * nt + r;
        if (kv < KK) {
#pragma unroll
            for (int reg = 0; reg < 4; ++reg) {
                int t2 = 16 * w + q * 4 + reg;
                ob[(size_t)t2 * NF + kv] = __float2bfloat16(o[reg]);
            }
        }
    }
}

// ---------------- x = LN(delta + x) * g + b  — one wave per row, vectorized ----------------
__global__ __launch_bounds__(256) void add_ln_kernel(const bf16* __restrict__ delta,
                                                     bf16* __restrict__ x,
                                                     const float* __restrict__ g,
                                                     const float* __restrict__ bta,
                                                     int nrows) {
    const int w = threadIdx.x >> 6;
    const int lane = threadIdx.x & 63;
    const int row = blockIdx.x * 4 + w;
    if (row >= nrows) return;
    const bf16* dr = delta + (size_t)row * NF;
    bf16* xr = x + (size_t)row * KP;

    float v[3][4];
    float s1 = 0.f, s2 = 0.f;
#pragma unroll
    for (int s = 0; s < 3; ++s) {
        int c = s * 256 + lane * 4;
        if (c < DD) {
            bf16x4 dv = *(const bf16x4*)(dr + c);
            bf16x4 xv = *(const bf16x4*)(xr + c);
#pragma unroll
            for (int j = 0; j < 4; ++j) {
                float t = (float)dv[j] + (float)xv[j];
                v[s][j] = t;
                s1 += t; s2 += t * t;
            }
        } else {
#pragma unroll
            for (int j = 0; j < 4; ++j) v[s][j] = 0.f;
        }
    }
#pragma unroll
    for (int o = 32; o > 0; o >>= 1) {
        s1 += __shfl_xor(s1, o, 64);
        s2 += __shfl_xor(s2, o, 64);
    }
    const float mean = s1 * (1.f / DD);
    const float var = s2 * (1.f / DD) - mean * mean;
    const float rstd = rsqrtf(var + 1e-5f);
#pragma unroll
    for (int s = 0; s < 3; ++s) {
        int c = s * 256 + lane * 4;
        if (c < DD) {
            float4 gv = *(const float4*)(g + c);
            float4 bv = *(const float4*)(bta + c);
            bf16x4 ov;
            ov[0] = (__bf16)((v[s][0] - mean) * rstd * gv.x + bv.x);
            ov[1] = (__bf16)((v[s][1] - mean) * rstd * gv.y + bv.y);
            ov[2] = (__bf16)((v[s][2] - mean) * rstd * gv.z + bv.z);
            ov[3] = (__bf16)((v[s][3] - mean) * rstd * gv.w + bv.w);
            *(bf16x4*)(xr + c) = ov;
        }
    }
}

__global__ __launch_bounds__(256) void final_kernel(const bf16* __restrict__ xc,
                                                    const float* __restrict__ Wc,
                                                    const float* __restrict__ bc,
                                                    float* __restrict__ out) {
    int b = blockIdx.x;
    int tid = threadIdx.x;
    const bf16* xb = xc + (size_t)b * TT * KP;
    float s = 0.f;
    for (int i = tid; i < TD; i += 256) {
        int t = i / DD, d = i - t * DD;
        s += toF(xb[(size_t)t * KP + d]) * Wc[i];
    }
    for (int o = 32; o > 0; o >>= 1) s += __shfl_down(s, o, 64);
    __shared__ float red[4];
    int lane = tid & 63, w = tid >> 6;
    if (lane == 0) red[w] = s;
    __syncthreads();
    if (tid == 0) out[b] = red[0] + red[1] + red[2] + red[3] + bc[0];
}

extern "C" void kernel_launch(void* const* d_in, const int* in_sizes, int n_in,
                              void* d_out, int out_size, void* d_ws, size_t ws_size,
                              hipStream_t stream) {
    const int* ids    = (const int*)d_in[0];
    const float* embed = (const float*)d_in[1];
    const float* pos  = (const float*)d_in[2];
    const float* Wq   = (const float*)d_in[3];
    const float* Wk   = (const float*)d_in[4];
    const float* Wv   = (const float*)d_in[5];
    const float* W1   = (const float*)d_in[6];
    const float* b1   = (const float*)d_in[7];
    const float* W2   = (const float*)d_in[8];
    const float* b2   = (const float*)d_in[9];
    const float* ln1g = (const float*)d_in[10];
    const float* ln1b = (const float*)d_in[11];
    const float* ln2g = (const float*)d_in[12];
    const float* ln2b = (const float*)d_in[13];
    const float* Wc   = (const float*)d_in[14];
    const float* bc   = (const float*)d_in[15];
    float* out = (float*)d_out;

    const size_t wqkvB = (size_t)LL * NQ * KP * 2;
    const size_t wffB  = (size_t)LL * NF * KP * 2;
    const size_t fixed = wqkvB + 2 * wffB;
    const size_t perB  = (size_t)TT * 2 * (KP + NQ + NF);

    int bch = BB;
    while (bch > 8 && fixed + (size_t)bch * perB > ws_size) bch >>= 1;
    int nch = BB / bch;
    int rows = bch * TT;

    char* p = (char*)d_ws;
    bf16* wTt = (bf16*)p;  p += wqkvB;
    bf16* W1t = (bf16*)p;  p += wffB;
    bf16* W2t = (bf16*)p;  p += wffB;
    bf16* xc  = (bf16*)p;  p += (size_t)rows * KP * 2;
    bf16* scr = (bf16*)p;  p += (size_t)rows * NQ * 2;
    bf16* dch = (bf16*)p;

    prep_wqkv<<<(LL * NQ * KP + 255) / 256, 256, 0, stream>>>(Wq, Wk, Wv, wTt);
    prep_wt<<<(LL * NF * KP + 255) / 256, 256, 0, stream>>>(W1, W1t);
    prep_wt<<<(LL * NF * KP + 255) / 256, 256, 0, stream>>>(W2, W2t);

    dim3 gq(NQ / 128, rows / 128);
    dim3 gf(NF / 128, rows / 128);
    const size_t attn_lds = (size_t)(160 + 96) * TP * 2;   // 53,248 B
    const int lnGrid = (rows + 3) / 4;

    for (int c = 0; c < nch; ++c) {
        embed_kernel<<<(rows * KP + 255) / 256, 256, 0, stream>>>(
            ids + (size_t)c * rows, embed, pos, xc, rows);
        for (int l = 0; l < LL; ++l) {
            mfma_gemm<<<gq, 256, 0, stream>>>(
                xc, KP, wTt + (size_t)l * NQ * KP, scr, NQ, N3,
                (const float*)nullptr, 0);
            attn_mfma<<<bch * HH, 320, attn_lds, stream>>>(scr, dch);
            add_ln_kernel<<<lnGrid, 256, 0, stream>>>(dch, xc, ln1g + l * DD, ln1b + l * DD, rows);
            mfma_gemm<<<gf, 256, 0, stream>>>(
                xc, KP, W1t + (size_t)l * NF * KP, scr, NF, HK,
                b1 + (size_t)l * HK, 1);
            mfma_gemm<<<gf, 256, 0, stream>>>(
                scr, NF, W2t + (size_t)l * NF * KP, dch, NF, DD,
                b2 + (size_t)l * DD, 0);
            add_ln_kernel<<<lnGrid, 256, 0, stream>>>(dch, xc, ln2g + l * DD, ln2b + l * DD, rows);
        }
        final_kernel<<<bch, 256, 0, stream>>>(xc, Wc, bc, out + (size_t)c * bch);
    }
}